// Round 6
// baseline (152.968 us; speedup 1.0000x reference)
//
#include <hip/hip_runtime.h>

// R6: 32-row tiles (2 per (n,c), grid 8192, block 512). R5 per-thread stage
// bodies preserved (packed v2f math); only the tiling/geometry changes.
//   S0 load -> S1 V-up(x2) -> S2 [H-up + act + H-down] fused -> S4 V-down + store.
//   s_in[42 x 80] : input rows gy0-5..gy0+36, cols -5..74 zero-padded  (bufA)
//   t1  [74 x 80] : vertical x2 up, cols 0..73 valid                   (bufB)
//   t3  [74 x 72] : H-up+act+H-down result, cols 0..63 valid           (bufA)
// LDS = (5328 + 5928 + 24)*4 ~= 45.1 KB -> 3 blocks/CU (24 waves).
// Rationale: R5 showed VALUBusy 97->71 with flat time => non-VALU floor
// (LDS pipe + barriers + halo) scales with blocks/image; bigger tile cuts
// t1 rows/output 2.625->2.3125 (-12%) and input halo -19%.
#define SIN 80
#define ST1 80
#define ST3 72

typedef float v2f __attribute__((ext_vector_type(2)));

static __device__ __forceinline__ v2f fma2(v2f a, v2f b, v2f c) {
    return __builtin_elementwise_fma(a, b, c);
}
static __device__ __forceinline__ v2f bcast2(float s) {
    v2f r; r.x = s; r.y = s; return r;
}
static __device__ __forceinline__ v2f mk2(float a, float b) {
    v2f r; r.x = a; r.y = b; return r;
}

__global__ __launch_bounds__(512, 6)
void synth_fused(const float* __restrict__ x, const float* __restrict__ bias,
                 const float* __restrict__ fu, const float* __restrict__ fd,
                 float* __restrict__ out)
{
    __shared__ __align__(16) float bufA[5328];   // s_in 42x80=3360 / t3 74x72=5328
    __shared__ __align__(16) float bufB[5928];   // t1 74x80=5920 + slack (q=5 reads to idx 5921)
    __shared__ float sfilt[24];
    float* const s_in = bufA;
    float* const s_t3 = bufA;
    float* const s_t1 = bufB;

    const int tid  = threadIdx.x;
    const int bx   = blockIdx.x;
    const int tile = bx & 1;
    const int nc   = bx >> 1;
    const int gy0  = tile << 5;

    if (tid < 24) sfilt[tid] = (tid < 12) ? fu[tid] : fd[tid - 12];
    const float bc = bias[nc & 511];
    const float* __restrict__ xc = x + ((size_t)nc << 12);

    // ---- S0: load 42 rows x 64 cols (float4, coalesced) + zero pad cols ----
    #pragma unroll
    for (int it = 0; it < 2; ++it) {
        int idx = tid + (it << 9);
        if (idx < 672) {                         // 42 rows * 16 float4
            int r  = idx >> 4;
            int c4 = (idx & 15) << 2;
            int gy = gy0 - 5 + r;
            float4 v = make_float4(0.f, 0.f, 0.f, 0.f);
            if ((unsigned)gy < 64u)
                v = *reinterpret_cast<const float4*>(xc + (gy << 6) + c4);
            float* dst = s_in + r * SIN + 5 + c4;
            dst[0] = v.x; dst[1] = v.y; dst[2] = v.z; dst[3] = v.w;
        }
    }
    #pragma unroll
    for (int it = 0; it < 2; ++it) {                 // 42*16 pad slots (cols 0..4, 69..79)
        int idx = tid + (it << 9);
        if (idx < 672) {
            int r  = idx >> 4;
            int pc = idx & 15;
            int c  = (pc < 5) ? pc : (64 + pc);
            s_in[r * SIN + c] = 0.0f;
        }
    }
    __syncthreads();

    // coefficient PAIRS
    v2f upk[6], gpk[6];
    #pragma unroll
    for (int j = 0; j < 6; ++j) {
        upk[j] = mk2(sfilt[10 - 2*j], sfilt[11 - 2*j]);   // {even,odd} up phases
        gpk[j] = mk2(sfilt[23 - 2*j], sfilt[22 - 2*j]);   // {g[2j], g[2j+1]}
    }

    // ---- S1: vertical x2 up, 1 col/thread. 444 threads (g 0..5, c 0..73) ----
    // group g owns m = m0..m0+cnt-1, m0 = (g==0)?0:6g+1, cnt = (g==0)?7:6.
    // {t1[2m][c], t1[2m+1][c]} = sum_j upk[j] * {s_in[m+j][c]}bcast
    if (tid < 444) {
        const int g  = tid / 74;
        const int c  = tid - 74 * g;
        const int m0 = 6 * g + (g > 0);
        const float* ip = s_in + m0 * SIN + c;
        float rv[12];
        #pragma unroll
        for (int j = 0; j < 11; ++j) rv[j] = ip[j * SIN];
        rv[11] = (g == 0) ? ip[11 * SIN] : 0.0f;
        float* op = s_t1 + (2 * m0) * ST1 + c;
        #pragma unroll
        for (int mm = 0; mm < 6; ++mm) {
            v2f acc = upk[0] * bcast2(rv[mm]);
            #pragma unroll
            for (int j = 1; j < 6; ++j)
                acc = fma2(upk[j], bcast2(rv[mm + j]), acc);
            op[(2*mm) * ST1]     = acc.x;
            op[(2*mm + 1) * ST1] = acc.y;
        }
        if (g == 0) {                               // 7th m for group 0
            v2f acc = upk[0] * bcast2(rv[6]);
            #pragma unroll
            for (int j = 1; j < 6; ++j)
                acc = fma2(upk[j], bcast2(rv[6 + j]), acc);
            op[12 * ST1] = acc.x;
            op[13 * ST1] = acc.y;
        }
    }
    __syncthreads();

    // fold x4 up-gain AND sqrt2 act-gain into H-up taps; sqrt2 into bias
    const float S42 = 4.0f * 1.41421356237309515f;
    v2f upk2[6];
    #pragma unroll
    for (int j = 0; j < 6; ++j) upk2[j] = upk[j] * S42;
    const float bcs = bc * 1.41421356237309515f;

    // ---- S2: fused H-up + lrelu/clamp + H-down. 444 threads (r 0..73, q 0..5) ----
    // t2p[i] = act( sum_j upk2[j]*{w[i+j]}bcast + {bcs,bcs} ),  i 0..16
    //   act(z) = med3(max(z, 0.2z), -256, 256)   [sqrt2 already in taps/bias]
    // t3[r][12q+oi] = hadd( sum_j gpk[j]*t2p[oi+j] ),  oi 0..11
    // q=5: t1 cols >=74 garbage -> feeds only t3 cols >=64 (pad, never read).
    if (tid < 444) {
        const int r = tid / 6;
        const int q = tid - 6 * r;
        const float* t1r = s_t1 + r * ST1 + 12 * q;
        float w[22];
        #pragma unroll
        for (int j = 0; j < 11; ++j) {
            v2f v2 = *reinterpret_cast<const v2f*>(t1r + 2 * j);
            w[2*j] = v2.x; w[2*j+1] = v2.y;
        }
        const v2f bc2 = bcast2(bcs);
        v2f t2p[17];
        #pragma unroll
        for (int i = 0; i < 17; ++i) {
            v2f acc = bc2;
            #pragma unroll
            for (int j = 0; j < 6; ++j)
                acc = fma2(upk2[j], bcast2(w[i + j]), acc);
            v2f mx = __builtin_elementwise_max(acc, acc * 0.2f);
            t2p[i] = mk2(__builtin_amdgcn_fmed3f(mx.x, -256.0f, 256.0f),
                         __builtin_amdgcn_fmed3f(mx.y, -256.0f, 256.0f));
        }
        float* t3r = s_t3 + r * ST3 + 12 * q;
        #pragma unroll
        for (int i = 0; i < 3; ++i) {
            float4 o4;
            float* op = &o4.x;
            #pragma unroll
            for (int s = 0; s < 4; ++s) {
                const int oi = 4 * i + s;
                v2f acc = gpk[0] * t2p[oi];
                #pragma unroll
                for (int j = 1; j < 6; ++j) acc = fma2(gpk[j], t2p[oi + j], acc);
                op[s] = acc.x + acc.y;
            }
            *reinterpret_cast<float4*>(t3r + 4 * i) = o4;
        }
    }
    __syncthreads();

    // ---- S4: vertical /2 down, 1 col/thread, 512 threads (rc 0..7, c 0..63) ----
    // out rows gy0+4rc..+3 at col c; pairs vp[m] = {t3[8rc+2m][c], t3[8rc+2m+1][c]}
    {
        const int c  = tid & 63;
        const int rc = tid >> 6;
        const float* t3c = s_t3 + (rc << 3) * ST3 + c;
        v2f vp[9];
        #pragma unroll
        for (int m = 0; m < 9; ++m)
            vp[m] = mk2(t3c[(2*m) * ST3], t3c[(2*m + 1) * ST3]);
        float* op = out + ((size_t)nc << 12) + ((size_t)(gy0 + (rc << 2)) << 6) + c;
        #pragma unroll
        for (int i = 0; i < 4; ++i) {
            v2f acc = gpk[0] * vp[i];
            #pragma unroll
            for (int j = 1; j < 6; ++j) acc = fma2(gpk[j], vp[i + j], acc);
            op[(size_t)(i << 6)] = acc.x + acc.y;
        }
    }
}

extern "C" void kernel_launch(void* const* d_in, const int* in_sizes, int n_in,
                              void* d_out, int out_size, void* d_ws, size_t ws_size,
                              hipStream_t stream) {
    const float* x    = (const float*)d_in[0];
    const float* bias = (const float*)d_in[1];
    const float* fu   = (const float*)d_in[2];
    const float* fd   = (const float*)d_in[3];
    float* out        = (float*)d_out;

    dim3 grid(8 * 512 * 2);   // (n*c) x 2 row-tiles of 32x64
    dim3 block(512);
    hipLaunchKernelGGL(synth_fused, grid, block, 0, stream, x, bias, fu, fd, out);
}